// Round 14
// baseline (915.695 us; speedup 1.0000x reference)
//
#include <hip/hip_runtime.h>

// N=1024, D=16, H=32, 3H=96.  All tensors fp32 (per reference dtypes).

typedef _Float16 hv2 __attribute__((ext_vector_type(2)));
typedef _Float16 hv8 __attribute__((ext_vector_type(8)));
typedef float    fv4 __attribute__((ext_vector_type(4)));
typedef unsigned uv4 __attribute__((ext_vector_type(4)));

// pack two fp32 -> f16 pair bits (v_cvt_pkrtz_f16_f32)
__device__ __forceinline__ unsigned pkh(float a, float b) {
    auto t = __builtin_amdgcn_cvt_pkrtz(a, b);
    return __builtin_bit_cast(unsigned, t);
}
__device__ __forceinline__ fv4 splat4(float v) { return fv4{v, v, v, v}; }
// compiler-only memory fence (R13-proven): per-wave DS is in-order in HW;
// this stops the compiler from hoisting LDS h-reads above the h-write.
__device__ __forceinline__ void cfence() { __asm__ __volatile__("" ::: "memory"); }
// fast reciprocal: v_rcp_f32 (~1 ulp) instead of the ~11-inst div sequence
#if __has_builtin(__builtin_amdgcn_rcpf)
__device__ __forceinline__ float frcp(float x) { return __builtin_amdgcn_rcpf(x); }
#else
__device__ __forceinline__ float frcp(float x) { return 1.f / x; }
#endif
// dot2: c += a.x*b.x + a.y*b.y   (f16 inputs, f32 accumulate)
#if __has_builtin(__builtin_amdgcn_fdot2)
__device__ __forceinline__ float d2(unsigned a, unsigned b, float c) {
    return __builtin_amdgcn_fdot2(__builtin_bit_cast(hv2, a),
                                  __builtin_bit_cast(hv2, b), c, false);
}
#else
__device__ __forceinline__ float d2(unsigned a, unsigned b, float c) {
    hv2 x = __builtin_bit_cast(hv2, a), y = __builtin_bit_cast(hv2, b);
    return fmaf((float)x.x, (float)y.x, fmaf((float)x.y, (float)y.y, c));
}
#endif

// ---------------------------------------------------------------------------
// K1/K3: pairwise rank-split (unchanged, proven).
// ---------------------------------------------------------------------------
__global__ void proj1_kernel(const float* __restrict__ x, const float* __restrict__ w,
                             const float* __restrict__ bias,
                             float* __restrict__ A, float* __restrict__ B) {
    int idx = blockIdx.x * 256 + threadIdx.x;      // 0..32767
    int i = idx >> 5, h = idx & 31;
    float sa = bias[h];
    float sb = 0.f;
#pragma unroll
    for (int d = 0; d < 16; ++d) {
        float xv = x[i * 16 + d];
        float wa = w[h * 32 + d];
        float wb = w[h * 32 + 16 + d];
        sa += (wa - wb) * xv;
        sb += wb * xv;
    }
    A[i * 32 + h] = sa;
    B[i * 32 + h] = sb;
}

__global__ void proj2_kernel(const float* __restrict__ h1, const float* __restrict__ w,
                             const float* __restrict__ bias,
                             float* __restrict__ A, float* __restrict__ B) {
    int idx = blockIdx.x * 256 + threadIdx.x;      // 0..32767
    int i = idx >> 5, h = idx & 31;
    float sa = bias[h];
    float sb = 0.f;
#pragma unroll
    for (int k = 0; k < 32; ++k) {
        float hv = h1[i * 32 + k];
        float wa = w[h * 64 + k];
        float wb = w[h * 64 + 32 + k];
        sa += (wa - wb) * hv;
        sb += wb * hv;
    }
    A[i * 32 + h] = sa;
    B[i * 32 + h] = sb;
}

// ---------------------------------------------------------------------------
// GRU: FOUR chains per wave, 256 blocks (1 wave/CU -> no LDS contention).
// Lane l: chain q = l>>4 (block-local), hidden slot s = l&15 -- this lane
// owns hidden indices s AND s+16 of chain q via (k,k+16) f16 pair packing.
//
// CHUNK phase (per 16 steps, off the serial path): for each chain P,
//   XG_P[t][g] = Wih.relu(A_P + B_t) + bih via 6 MFMAs (R11/R13-proven
//   k-slot frag layout) -> xg[P][6][16][17].
// SERIAL phase (per step): h pairs (h_j, h_j+16) of chain q in hlds[q*16+j];
//   4 quarter-broadcast ds_read_b128 -> H0..H3; the SAME 96 v_dot2
//   instructions compute r/z/n h-side for hidden s and s+16 of all 4 chains
//   (per-lane data).  Gates + update fully in-lane (v_rcp sigmoids/tanh);
//   publish pkh(h_s, h_s16) -> 1 ds_write per lane (2-way banks, free).
//   cfence() orders the LDS round trip (R12 bug, R13 fix).
// ---------------------------------------------------------------------------
__global__ __launch_bounds__(64, 1) void gru_kernel(
    const float* __restrict__ A, const float* __restrict__ B,
    const float* __restrict__ wih, const float* __restrict__ whh,
    const float* __restrict__ bih, const float* __restrict__ bhh,
    float* __restrict__ h_out) {
    const int l = threadIdx.x;         // 0..63
    const int q = l >> 4;              // k-slot group == block-local chain id
    const int m0 = l & 15;             // MFMA col == hidden slot s
    const int cbase = blockIdx.x * 4;

    __shared__ float xg[4][6][16][17]; // [chain][tile][t_local][col] (+pad)
    __shared__ unsigned hlds[64];      // [chain*16 + j] = pkh(h_j, h_j+16)

    // ---- chunk-phase weights: Wih B-frags (k-slot (k,k+16) pairs) ----
    hv8 WI[6];
#pragma unroll
    for (int T = 0; T < 6; ++T) {
        int g = 16 * T + m0;
        uv4 wi;
#pragma unroll
        for (int r = 0; r < 4; ++r) {
            int lo = 4 * q + r;
            wi[r] = pkh(wih[g * 32 + lo], wih[g * 32 + lo + 16]);
        }
        WI[T] = __builtin_bit_cast(hv8, wi);
    }
    float bi[6];
#pragma unroll
    for (int T = 0; T < 6; ++T) bi[T] = bih[16 * T + m0];

    // ---- serial-phase weights: whh rows for (rA,rB,zA,zB,nA,nB) ----
    //      A = hidden s, B = hidden s+16; pairs (k, k+16).
    unsigned W6[6][16];
    float bh6[6];
    {
        const int rows[6] = {m0, m0 + 16, m0 + 32, m0 + 48, m0 + 64, m0 + 80};
#pragma unroll
        for (int g = 0; g < 6; ++g) {
            bh6[g] = bhh[rows[g]];
#pragma unroll
            for (int k = 0; k < 16; ++k)
                W6[g][k] = pkh(whh[rows[g] * 32 + k], whh[rows[g] * 32 + k + 16]);
        }
    }

    const fv4* A4 = (const fv4*)A;     // [chain*8 + slot]
    const fv4* B4 = (const fv4*)B;     // [t*8 + slot]
    fv4 aloP[4], ahiP[4];
#pragma unroll
    for (int P = 0; P < 4; ++P) {
        aloP[P] = A4[(cbase + P) * 8 + q];
        ahiP[P] = A4[(cbase + P) * 8 + 4 + q];
    }

    // chunk staging: this lane supplies timestep c0 + m0, k-slots of group q
    fv4 blo = B4[m0 * 8 + q], bhi = B4[m0 * 8 + 4 + q];   // chunk 0

    float hA = 0.f, hB = 0.f;          // h_s, h_{s+16} of chain q
    hlds[l] = 0u;

    const uv4* hqp = (const uv4*)(hlds + q * 16);

    for (int c0 = 0; c0 < 1024; c0 += 16) {
        // ---- X-chunks: 6 MFMAs per chain over 16 timesteps -> LDS ----
#pragma unroll
        for (int P = 0; P < 4; ++P) {
            uv4 xb;
#pragma unroll
            for (int r = 0; r < 4; ++r)
                xb[r] = pkh(fmaxf(aloP[P][r] + blo[r], 0.f),
                            fmaxf(ahiP[P][r] + bhi[r], 0.f));
            hv8 xf = __builtin_bit_cast(hv8, xb);
#pragma unroll
            for (int T = 0; T < 6; ++T) {
                fv4 D = __builtin_amdgcn_mfma_f32_16x16x32_f16(
                    xf, WI[T], splat4(bi[T]), 0, 0, 0);
#pragma unroll
                for (int r = 0; r < 4; ++r) xg[P][T][4 * q + r][m0] = D[r];
            }
        }

        int nc = (c0 + 16) & 1023;     // prefetch next chunk's B rows
        blo = B4[(nc + m0) * 8 + q];
        bhi = B4[(nc + m0) * 8 + 4 + q];

        __syncthreads();

        // preload X pre-acts for step 0: tiles {0..5} = {rA,rB,zA,zB,nA,nB}
        float x6[6];
#pragma unroll
        for (int g = 0; g < 6; ++g) x6[g] = xg[q][g][0][m0];

#pragma unroll 4
        for (int it = 0; it < 16; ++it) {
            // ---- h pairs of chain q (quarter-broadcast b128 reads) ----
            cfence();
            uv4 H0 = hqp[0], H1 = hqp[1], H2 = hqp[2], H3 = hqp[3];

            // ---- 96 dot2: 6 gate-rows x 2 split accumulators ----
            float a0[6], a1[6];
#pragma unroll
            for (int g = 0; g < 6; ++g) { a0[g] = bh6[g]; a1[g] = 0.f; }
#pragma unroll
            for (int k = 0; k < 4; ++k) {
#pragma unroll
                for (int g = 0; g < 6; ++g) {
                    a0[g] = d2(W6[g][k],      H0[k], a0[g]);
                    a1[g] = d2(W6[g][k + 8],  H2[k], a1[g]);
                    a0[g] = d2(W6[g][k + 4],  H1[k], a0[g]);
                    a1[g] = d2(W6[g][k + 12], H3[k], a1[g]);
                }
            }

            // ---- prefetch next step's X (off the critical path) ----
            float nx6[6];
            if (it < 15) {
#pragma unroll
                for (int g = 0; g < 6; ++g) nx6[g] = xg[q][g][it + 1][m0];
            } else {
#pragma unroll
                for (int g = 0; g < 6; ++g) nx6[g] = x6[g];
            }

            // ---- gates + update, fully in-lane (rcp-based sigmoid/tanh) ----
            float hrA = a0[0] + a1[0], hrB = a0[1] + a1[1];
            float hzA = a0[2] + a1[2], hzB = a0[3] + a1[3];
            float hnA = a0[4] + a1[4], hnB = a0[5] + a1[5];
            float rA = frcp(1.f + __expf(-(x6[0] + hrA)));
            float rB = frcp(1.f + __expf(-(x6[1] + hrB)));
            float zA = frcp(1.f + __expf(-(x6[2] + hzA)));
            float zB = frcp(1.f + __expf(-(x6[3] + hzB)));
            float nA = 1.f - 2.f * frcp(__expf(2.f * (x6[4] + rA * hnA)) + 1.f);
            float nB = 1.f - 2.f * frcp(__expf(2.f * (x6[5] + rB * hnB)) + 1.f);
            hA = (1.f - zA) * nA + zA * hA;
            hB = (1.f - zB) * nB + zB * hB;

            // ---- publish pair (h_s, h_s+16) for the next step ----
            hlds[q * 16 + m0] = pkh(hA, hB);
            cfence();

#pragma unroll
            for (int g = 0; g < 6; ++g) x6[g] = nx6[g];
        }
        __syncthreads();   // next chunk's stores vs this chunk's reads
    }

    h_out[(cbase + q) * 32 + m0]      = hA;
    h_out[(cbase + q) * 32 + m0 + 16] = hB;
}

// ---------------------------------------------------------------------------
// K5: classifier. out[i,o] = sum_k clf_w[o,k]*h2[i,k] + clf_b[o]  (fp32 out)
// ---------------------------------------------------------------------------
__global__ void clf_kernel(const float* __restrict__ h2v, const float* __restrict__ w,
                           const float* __restrict__ bias, float* __restrict__ out) {
    int idx = blockIdx.x * 256 + threadIdx.x;      // 0..3071
    if (idx >= 3072) return;
    int i = idx / 3, o = idx - i * 3;
    float s = bias[o];
#pragma unroll
    for (int k = 0; k < 32; ++k) s += w[o * 32 + k] * h2v[i * 32 + k];
    out[idx] = s;
}

extern "C" void kernel_launch(void* const* d_in, const int* in_sizes, int n_in,
                              void* d_out, int out_size, void* d_ws, size_t ws_size,
                              hipStream_t stream) {
    const float* x       = (const float*)d_in[0];
    const float* p1w     = (const float*)d_in[1];
    const float* p1b     = (const float*)d_in[2];
    const float* g1_wih  = (const float*)d_in[3];
    const float* g1_whh  = (const float*)d_in[4];
    const float* g1_bih  = (const float*)d_in[5];
    const float* g1_bhh  = (const float*)d_in[6];
    const float* p2w     = (const float*)d_in[7];
    const float* p2b     = (const float*)d_in[8];
    const float* g2_wih  = (const float*)d_in[9];
    const float* g2_whh  = (const float*)d_in[10];
    const float* g2_bih  = (const float*)d_in[11];
    const float* g2_bhh  = (const float*)d_in[12];
    const float* clfw    = (const float*)d_in[13];
    const float* clfb    = (const float*)d_in[14];

    // Workspace layout (reused across stages; 3 x 32768 floats = 384 KB):
    float* ws = (float*)d_ws;
    float* A  = ws;              // A1 then A2
    float* Bt = ws + 32768;      // B1 then B2
    float* h  = ws + 65536;      // h1 then h2

    proj1_kernel<<<128, 256, 0, stream>>>(x, p1w, p1b, A, Bt);
    gru_kernel<<<256, 64, 0, stream>>>(A, Bt, g1_wih, g1_whh, g1_bih, g1_bhh, h);
    proj2_kernel<<<128, 256, 0, stream>>>(h, p2w, p2b, A, Bt);
    gru_kernel<<<256, 64, 0, stream>>>(A, Bt, g2_wih, g2_whh, g2_bih, g2_bhh, h);
    clf_kernel<<<12, 256, 0, stream>>>(h, clfw, clfb, (float*)d_out);
}

// Round 15
// 580.264 us; speedup vs baseline: 1.5781x; 1.5781x over previous
//
#include <hip/hip_runtime.h>

// N=1024, D=16, H=32, 3H=96.  All tensors fp32 (per reference dtypes).

typedef _Float16 hv2 __attribute__((ext_vector_type(2)));
typedef _Float16 hv8 __attribute__((ext_vector_type(8)));
typedef float    fv4 __attribute__((ext_vector_type(4)));
typedef unsigned uv4 __attribute__((ext_vector_type(4)));

// pack two fp32 -> f16 pair bits (v_cvt_pkrtz_f16_f32)
__device__ __forceinline__ unsigned pkh(float a, float b) {
    auto t = __builtin_amdgcn_cvt_pkrtz(a, b);
    return __builtin_bit_cast(unsigned, t);
}
__device__ __forceinline__ fv4 splat4(float v) { return fv4{v, v, v, v}; }
// compiler-only memory fence (R13-proven): per-wave DS is in-order in HW;
// this stops the compiler from hoisting LDS h-reads above the h-write.
__device__ __forceinline__ void cfence() { __asm__ __volatile__("" ::: "memory"); }
// fast reciprocal: v_rcp_f32 (~1 ulp; R14-verified accuracy-neutral) instead
// of the ~11-inst IEEE div expansion (~30-40 cyc on the serial gate chain).
#if __has_builtin(__builtin_amdgcn_rcpf)
__device__ __forceinline__ float frcp(float x) { return __builtin_amdgcn_rcpf(x); }
#else
__device__ __forceinline__ float frcp(float x) { return 1.f / x; }
#endif
// dot2: c += a.x*b.x + a.y*b.y   (f16 inputs, f32 accumulate)
#if __has_builtin(__builtin_amdgcn_fdot2)
__device__ __forceinline__ float d2(unsigned a, unsigned b, float c) {
    return __builtin_amdgcn_fdot2(__builtin_bit_cast(hv2, a),
                                  __builtin_bit_cast(hv2, b), c, false);
}
#else
__device__ __forceinline__ float d2(unsigned a, unsigned b, float c) {
    hv2 x = __builtin_bit_cast(hv2, a), y = __builtin_bit_cast(hv2, b);
    return fmaf((float)x.x, (float)y.x, fmaf((float)x.y, (float)y.y, c));
}
#endif
// neighbor (lane^1) via DPP quad_perm(1,0,3,2) -- VALU, no LDS
#if __has_builtin(__builtin_amdgcn_mov_dpp)
__device__ __forceinline__ float nbr1(float v) {
    return __int_as_float(
        __builtin_amdgcn_mov_dpp(__float_as_int(v), 0xB1, 0xF, 0xF, true));
}
#else
__device__ __forceinline__ float nbr1(float v) {
    return __int_as_float(__builtin_amdgcn_ds_swizzle(__float_as_int(v), 0x041F));
}
#endif

// ---------------------------------------------------------------------------
// K1/K3: pairwise rank-split (unchanged, proven).
// ---------------------------------------------------------------------------
__global__ void proj1_kernel(const float* __restrict__ x, const float* __restrict__ w,
                             const float* __restrict__ bias,
                             float* __restrict__ A, float* __restrict__ B) {
    int idx = blockIdx.x * 256 + threadIdx.x;      // 0..32767
    int i = idx >> 5, h = idx & 31;
    float sa = bias[h];
    float sb = 0.f;
#pragma unroll
    for (int d = 0; d < 16; ++d) {
        float xv = x[i * 16 + d];
        float wa = w[h * 32 + d];
        float wb = w[h * 32 + 16 + d];
        sa += (wa - wb) * xv;
        sb += wb * xv;
    }
    A[i * 32 + h] = sa;
    B[i * 32 + h] = sb;
}

__global__ void proj2_kernel(const float* __restrict__ h1, const float* __restrict__ w,
                             const float* __restrict__ bias,
                             float* __restrict__ A, float* __restrict__ B) {
    int idx = blockIdx.x * 256 + threadIdx.x;      // 0..32767
    int i = idx >> 5, h = idx & 31;
    float sa = bias[h];
    float sb = 0.f;
#pragma unroll
    for (int k = 0; k < 32; ++k) {
        float hv = h1[i * 32 + k];
        float wa = w[h * 64 + k];
        float wb = w[h * 64 + 32 + k];
        sa += (wa - wb) * hv;
        sb += wb * hv;
    }
    A[i * 32 + h] = sa;
    B[i * 32 + h] = sb;
}

// ---------------------------------------------------------------------------
// GRU, one chain per wave, 1024 blocks (1 wave on every SIMD -- the R13
// occupancy shape; R14 proved 256 blocks idles 3/4 of the SIMDs).
//   CHUNK phase (per 16 steps, off the serial path): XG[t][g] =
//   Wih.relu(A_c+B_t)+bih via 6 MFMAs -> LDS xg[6][16][17].
//   SERIAL phase (per step): h publish via 1 predicated ds_write of f16
//   pairs + 4 wave-uniform ds_read_b128 (cfence-ordered, R13-proven);
//   48 v_dot2 in FOUR 4-deep split accumulator chains per gate; gates with
//   v_rcp sigmoid/tanh (divisions were ~100 cyc of serial critical path);
//   branch-free X prefetch; fully unrolled 16-step body.
// ---------------------------------------------------------------------------
__global__ __launch_bounds__(64, 1) void gru_kernel(
    const float* __restrict__ A, const float* __restrict__ B,
    const float* __restrict__ wih, const float* __restrict__ whh,
    const float* __restrict__ bih, const float* __restrict__ bhh,
    float* __restrict__ h_out) {
    const int l = threadIdx.x;         // 0..63
    const int q = l >> 4;              // k-slot group (chunk MFMA)
    const int m0 = l & 15;             // MFMA col
    const int m = l & 31;              // gate/hidden index (halves mirrored)
    const int c = blockIdx.x;          // chain

    __shared__ float xg[6][16][17];    // [tile][t_local][col] (+pad)
    __shared__ unsigned hlds[16];      // packed h pairs (h_2p, h_2p+1)

    // ---- chunk-phase weights: Wih B-frags (k-slot (k,k+16) pairs) ----
    hv8 WI[6];
#pragma unroll
    for (int T = 0; T < 6; ++T) {
        int g = 16 * T + m0;
        uv4 wi;
#pragma unroll
        for (int r = 0; r < 4; ++r) {
            int lo = 4 * q + r;
            wi[r] = pkh(wih[g * 32 + lo], wih[g * 32 + lo + 16]);
        }
        WI[T] = __builtin_bit_cast(hv8, wi);
    }
    float bi[6];
#pragma unroll
    for (int T = 0; T < 6; ++T) bi[T] = bih[16 * T + m0];

    // ---- serial-phase weights: whh rows m / 32+m / 64+m, adjacent pairs ----
    unsigned wr2[16], wz2[16], wn2[16];
#pragma unroll
    for (int k = 0; k < 16; ++k) {
        wr2[k] = pkh(whh[m * 32 + 2 * k],        whh[m * 32 + 2 * k + 1]);
        wz2[k] = pkh(whh[(32 + m) * 32 + 2 * k], whh[(32 + m) * 32 + 2 * k + 1]);
        wn2[k] = pkh(whh[(64 + m) * 32 + 2 * k], whh[(64 + m) * 32 + 2 * k + 1]);
    }
    const float bhr = bhh[m];
    const float bhz = bhh[32 + m];
    const float bhn = bhh[64 + m];

    const fv4* A4 = (const fv4*)A;     // [chain*8 + slot]
    const fv4* B4 = (const fv4*)B;     // [t*8 + slot]
    const fv4 alo = A4[c * 8 + q];
    const fv4 ahi = A4[c * 8 + 4 + q];

    // chunk staging: this lane supplies timestep c0 + m0
    fv4 blo = B4[m0 * 8 + q], bhi = B4[m0 * 8 + 4 + q];   // chunk 0

    float h_l = 0.f;                   // h_m (mirrored in both halves)
    if (l < 16) hlds[l] = 0u;

    const uv4* hq = (const uv4*)hlds;  // 4 x b128 wave-uniform reads

    for (int c0 = 0; c0 < 1024; c0 += 16) {
        // ---- X-chunk: 6 MFMAs over 16 timesteps -> LDS ----
        uv4 xb;
#pragma unroll
        for (int r = 0; r < 4; ++r)
            xb[r] = pkh(fmaxf(alo[r] + blo[r], 0.f), fmaxf(ahi[r] + bhi[r], 0.f));
        hv8 xf = __builtin_bit_cast(hv8, xb);

        int nc = (c0 + 16) & 1023;     // prefetch next chunk's B rows
        blo = B4[(nc + m0) * 8 + q];
        bhi = B4[(nc + m0) * 8 + 4 + q];

#pragma unroll
        for (int T = 0; T < 6; ++T) {
            fv4 D = __builtin_amdgcn_mfma_f32_16x16x32_f16(xf, WI[T], splat4(bi[T]), 0, 0, 0);
#pragma unroll
            for (int r = 0; r < 4; ++r) xg[T][4 * q + r][m0] = D[r];
        }
        __syncthreads();

        // preload X pre-acts for step 0 (bih folded in by the MFMA C-seed)
        const int Tq = m >> 4;         // 0 for m<16, 1 for m>=16
        const int mc = m & 15;
        float xr = xg[Tq][0][mc];
        float xz = xg[2 + Tq][0][mc];
        float xn = xg[4 + Tq][0][mc];

#pragma unroll
        for (int it = 0; it < 16; ++it) {
            // ---- h quads: ordered after the previous step's ds_write by
            //      per-wave in-order DS + compiler fence ----
            cfence();
            uv4 H0 = hq[0], H1 = hq[1], H2 = hq[2], H3 = hq[3];

            // ---- 48 dot2: r/z/n h-side, FOUR 4-deep chains each ----
            float hra = bhr, hrb = 0.f, hrc = 0.f, hrd = 0.f;
            float hza = bhz, hzb = 0.f, hzc = 0.f, hzd = 0.f;
            float hna = bhn, hnb = 0.f, hnc = 0.f, hnd = 0.f;
#pragma unroll
            for (int k = 0; k < 4; ++k) {
                hra = d2(wr2[k],      H0[k], hra);
                hrb = d2(wr2[k + 4],  H1[k], hrb);
                hrc = d2(wr2[k + 8],  H2[k], hrc);
                hrd = d2(wr2[k + 12], H3[k], hrd);
                hza = d2(wz2[k],      H0[k], hza);
                hzb = d2(wz2[k + 4],  H1[k], hzb);
                hzc = d2(wz2[k + 8],  H2[k], hzc);
                hzd = d2(wz2[k + 12], H3[k], hzd);
                hna = d2(wn2[k],      H0[k], hna);
                hnb = d2(wn2[k + 4],  H1[k], hnb);
                hnc = d2(wn2[k + 8],  H2[k], hnc);
                hnd = d2(wn2[k + 12], H3[k], hnd);
            }
            float hr = (hra + hrb) + (hrc + hrd);
            float hz = (hza + hzb) + (hzc + hzd);
            float hn = (hna + hnb) + (hnc + hnd);

            // ---- branch-free prefetch of next step's X ----
            int nt = (it + 1) & 15;
            float nxr = xg[Tq][nt][mc];
            float nxz = xg[2 + Tq][nt][mc];
            float nxn = xg[4 + Tq][nt][mc];

            // ---- gates + update, fully in-lane (rcp sigmoid/tanh) ----
            float r = frcp(1.f + __expf(-(xr + hr)));
            float z = frcp(1.f + __expf(-(xz + hz)));
            float n = 1.f - 2.f * frcp(__expf(2.f * (xn + r * hn)) + 1.f);
            h_l = (1.f - z) * n + z * h_l;

            // ---- publish packed h pairs for the next step ----
            unsigned hpk = pkh(h_l, nbr1(h_l));
            if (l < 32 && (l & 1) == 0) hlds[l >> 1] = hpk;
            cfence();

            xr = nxr; xz = nxz; xn = nxn;
        }
        __syncthreads();
    }

    if (l < 32) h_out[c * 32 + m] = h_l;
}

// ---------------------------------------------------------------------------
// K5: classifier. out[i,o] = sum_k clf_w[o,k]*h2[i,k] + clf_b[o]  (fp32 out)
// ---------------------------------------------------------------------------
__global__ void clf_kernel(const float* __restrict__ h2v, const float* __restrict__ w,
                           const float* __restrict__ bias, float* __restrict__ out) {
    int idx = blockIdx.x * 256 + threadIdx.x;      // 0..3071
    if (idx >= 3072) return;
    int i = idx / 3, o = idx - i * 3;
    float s = bias[o];
#pragma unroll
    for (int k = 0; k < 32; ++k) s += w[o * 32 + k] * h2v[i * 32 + k];
    out[idx] = s;
}

extern "C" void kernel_launch(void* const* d_in, const int* in_sizes, int n_in,
                              void* d_out, int out_size, void* d_ws, size_t ws_size,
                              hipStream_t stream) {
    const float* x       = (const float*)d_in[0];
    const float* p1w     = (const float*)d_in[1];
    const float* p1b     = (const float*)d_in[2];
    const float* g1_wih  = (const float*)d_in[3];
    const float* g1_whh  = (const float*)d_in[4];
    const float* g1_bih  = (const float*)d_in[5];
    const float* g1_bhh  = (const float*)d_in[6];
    const float* p2w     = (const float*)d_in[7];
    const float* p2b     = (const float*)d_in[8];
    const float* g2_wih  = (const float*)d_in[9];
    const float* g2_whh  = (const float*)d_in[10];
    const float* g2_bih  = (const float*)d_in[11];
    const float* g2_bhh  = (const float*)d_in[12];
    const float* clfw    = (const float*)d_in[13];
    const float* clfb    = (const float*)d_in[14];

    // Workspace layout (reused across stages; 3 x 32768 floats = 384 KB):
    float* ws = (float*)d_ws;
    float* A  = ws;              // A1 then A2
    float* Bt = ws + 32768;      // B1 then B2
    float* h  = ws + 65536;      // h1 then h2

    proj1_kernel<<<128, 256, 0, stream>>>(x, p1w, p1b, A, Bt);
    gru_kernel<<<1024, 64, 0, stream>>>(A, Bt, g1_wih, g1_whh, g1_bih, g1_bhh, h);
    proj2_kernel<<<128, 256, 0, stream>>>(h, p2w, p2b, A, Bt);
    gru_kernel<<<1024, 64, 0, stream>>>(A, Bt, g2_wih, g2_whh, g2_bih, g2_bhh, h);
    clf_kernel<<<12, 256, 0, stream>>>(h, clfw, clfb, (float*)d_out);
}

// Round 16
// 570.598 us; speedup vs baseline: 1.6048x; 1.0169x over previous
//
#include <hip/hip_runtime.h>

// N=1024, D=16, H=32, 3H=96.  All tensors fp32 (per reference dtypes).

typedef _Float16 hv2 __attribute__((ext_vector_type(2)));
typedef _Float16 hv8 __attribute__((ext_vector_type(8)));
typedef float    fv4 __attribute__((ext_vector_type(4)));
typedef unsigned uv4 __attribute__((ext_vector_type(4)));

// pack two fp32 -> f16 pair bits (v_cvt_pkrtz_f16_f32)
__device__ __forceinline__ unsigned pkh(float a, float b) {
    auto t = __builtin_amdgcn_cvt_pkrtz(a, b);
    return __builtin_bit_cast(unsigned, t);
}
__device__ __forceinline__ fv4 splat4(float v) { return fv4{v, v, v, v}; }
// compiler-only memory fence (R13-proven): per-wave DS is in-order in HW;
// this stops the compiler from hoisting LDS h-reads above the h-write.
__device__ __forceinline__ void cfence() { __asm__ __volatile__("" ::: "memory"); }
// fast reciprocal: v_rcp_f32 (~1 ulp; R14/R15-verified accuracy-neutral)
#if __has_builtin(__builtin_amdgcn_rcpf)
__device__ __forceinline__ float frcp(float x) { return __builtin_amdgcn_rcpf(x); }
#else
__device__ __forceinline__ float frcp(float x) { return 1.f / x; }
#endif
// dot2: c += a.x*b.x + a.y*b.y   (f16 inputs, f32 accumulate)
#if __has_builtin(__builtin_amdgcn_fdot2)
__device__ __forceinline__ float d2(unsigned a, unsigned b, float c) {
    return __builtin_amdgcn_fdot2(__builtin_bit_cast(hv2, a),
                                  __builtin_bit_cast(hv2, b), c, false);
}
#else
__device__ __forceinline__ float d2(unsigned a, unsigned b, float c) {
    hv2 x = __builtin_bit_cast(hv2, a), y = __builtin_bit_cast(hv2, b);
    return fmaf((float)x.x, (float)y.x, fmaf((float)x.y, (float)y.y, c));
}
#endif

// ---------------------------------------------------------------------------
// K1/K3: pairwise rank-split (unchanged, proven).
// ---------------------------------------------------------------------------
__global__ void proj1_kernel(const float* __restrict__ x, const float* __restrict__ w,
                             const float* __restrict__ bias,
                             float* __restrict__ A, float* __restrict__ B) {
    int idx = blockIdx.x * 256 + threadIdx.x;      // 0..32767
    int i = idx >> 5, h = idx & 31;
    float sa = bias[h];
    float sb = 0.f;
#pragma unroll
    for (int d = 0; d < 16; ++d) {
        float xv = x[i * 16 + d];
        float wa = w[h * 32 + d];
        float wb = w[h * 32 + 16 + d];
        sa += (wa - wb) * xv;
        sb += wb * xv;
    }
    A[i * 32 + h] = sa;
    B[i * 32 + h] = sb;
}

__global__ void proj2_kernel(const float* __restrict__ h1, const float* __restrict__ w,
                             const float* __restrict__ bias,
                             float* __restrict__ A, float* __restrict__ B) {
    int idx = blockIdx.x * 256 + threadIdx.x;      // 0..32767
    int i = idx >> 5, h = idx & 31;
    float sa = bias[h];
    float sb = 0.f;
#pragma unroll
    for (int k = 0; k < 32; ++k) {
        float hv = h1[i * 32 + k];
        float wa = w[h * 64 + k];
        float wb = w[h * 64 + 32 + k];
        sa += (wa - wb) * hv;
        sb += wb * hv;
    }
    A[i * 32 + h] = sa;
    B[i * 32 + h] = sb;
}

// ---------------------------------------------------------------------------
// GRU, one chain per wave, 1024 blocks (1 wave on every SIMD).
//   CHUNK phase (per 16 steps, off the serial path): XG[t][g] =
//   Wih.relu(A_c+B_t)+bih via 6 MFMAs -> LDS.  NEW: r/z tiles (0..3) store
//   exp(-XG) so the serial sigmoid is rcp(fma(e_x, exp(-hr), 1)) -- removes
//   the xr+hr add and starts the r-exponential one stage earlier (n waits
//   on r).  n tiles (4,5) store raw XG.
//   SERIAL phase (per step): h published as 32 f16 via ds_write_b16 (no
//   DPP/pack on the path), re-read as 4 wave-uniform ds_read_b128
//   (cfence-ordered, R13-proven); 48 v_dot2 in four 4-deep chains per gate;
//   v_rcp sigmoid/tanh; branch-free X prefetch; fully unrolled body.
// ---------------------------------------------------------------------------
__global__ __launch_bounds__(64, 1) void gru_kernel(
    const float* __restrict__ A, const float* __restrict__ B,
    const float* __restrict__ wih, const float* __restrict__ whh,
    const float* __restrict__ bih, const float* __restrict__ bhh,
    float* __restrict__ h_out) {
    const int l = threadIdx.x;         // 0..63
    const int q = l >> 4;              // k-slot group (chunk MFMA)
    const int m0 = l & 15;             // MFMA col
    const int m = l & 31;              // gate/hidden index (halves mirrored)
    const int c = blockIdx.x;          // chain

    __shared__ float xg[6][16][17];    // [tile][t_local][col] (+pad)
    __shared__ _Float16 hlds16[32];    // h as f16, element m = h_m

    // ---- chunk-phase weights: Wih B-frags (k-slot (k,k+16) pairs) ----
    hv8 WI[6];
#pragma unroll
    for (int T = 0; T < 6; ++T) {
        int g = 16 * T + m0;
        uv4 wi;
#pragma unroll
        for (int r = 0; r < 4; ++r) {
            int lo = 4 * q + r;
            wi[r] = pkh(wih[g * 32 + lo], wih[g * 32 + lo + 16]);
        }
        WI[T] = __builtin_bit_cast(hv8, wi);
    }
    float bi[6];
#pragma unroll
    for (int T = 0; T < 6; ++T) bi[T] = bih[16 * T + m0];

    // ---- serial-phase weights: whh rows m / 32+m / 64+m, adjacent pairs ----
    unsigned wr2[16], wz2[16], wn2[16];
#pragma unroll
    for (int k = 0; k < 16; ++k) {
        wr2[k] = pkh(whh[m * 32 + 2 * k],        whh[m * 32 + 2 * k + 1]);
        wz2[k] = pkh(whh[(32 + m) * 32 + 2 * k], whh[(32 + m) * 32 + 2 * k + 1]);
        wn2[k] = pkh(whh[(64 + m) * 32 + 2 * k], whh[(64 + m) * 32 + 2 * k + 1]);
    }
    const float bhr = bhh[m];
    const float bhz = bhh[32 + m];
    const float bhn = bhh[64 + m];

    const fv4* A4 = (const fv4*)A;     // [chain*8 + slot]
    const fv4* B4 = (const fv4*)B;     // [t*8 + slot]
    const fv4 alo = A4[c * 8 + q];
    const fv4 ahi = A4[c * 8 + 4 + q];

    // chunk staging: this lane supplies timestep c0 + m0
    fv4 blo = B4[m0 * 8 + q], bhi = B4[m0 * 8 + 4 + q];   // chunk 0

    float h_l = 0.f;                   // h_m (mirrored in both halves)
    if (l < 32) hlds16[l] = (_Float16)0.f;

    const uv4* hq = (const uv4*)hlds16;  // 4 x b128 wave-uniform reads

    for (int c0 = 0; c0 < 1024; c0 += 16) {
        // ---- X-chunk: 6 MFMAs over 16 timesteps -> LDS ----
        uv4 xb;
#pragma unroll
        for (int r = 0; r < 4; ++r)
            xb[r] = pkh(fmaxf(alo[r] + blo[r], 0.f), fmaxf(ahi[r] + bhi[r], 0.f));
        hv8 xf = __builtin_bit_cast(hv8, xb);

        int nc = (c0 + 16) & 1023;     // prefetch next chunk's B rows
        blo = B4[(nc + m0) * 8 + q];
        bhi = B4[(nc + m0) * 8 + 4 + q];

#pragma unroll
        for (int T = 0; T < 6; ++T) {
            fv4 D = __builtin_amdgcn_mfma_f32_16x16x32_f16(xf, WI[T], splat4(bi[T]), 0, 0, 0);
            if (T < 4) {               // r/z tiles: store exp(-XG) (off-path)
#pragma unroll
                for (int r = 0; r < 4; ++r) xg[T][4 * q + r][m0] = __expf(-D[r]);
            } else {                   // n tiles: raw XG
#pragma unroll
                for (int r = 0; r < 4; ++r) xg[T][4 * q + r][m0] = D[r];
            }
        }
        __syncthreads();

        // preload X pre-acts for step 0
        const int Tq = m >> 4;         // 0 for m<16, 1 for m>=16
        const int mc = m & 15;
        float er = xg[Tq][0][mc];      // exp(-xr)
        float ez = xg[2 + Tq][0][mc];  // exp(-xz)
        float xn = xg[4 + Tq][0][mc];  // raw xn

#pragma unroll
        for (int it = 0; it < 16; ++it) {
            // ---- h quads: ordered after the previous step's ds_write by
            //      per-wave in-order DS + compiler fence ----
            cfence();
            uv4 H0 = hq[0], H1 = hq[1], H2 = hq[2], H3 = hq[3];

            // ---- 48 dot2: r/z/n h-side, FOUR 4-deep chains each ----
            float hra = bhr, hrb = 0.f, hrc = 0.f, hrd = 0.f;
            float hza = bhz, hzb = 0.f, hzc = 0.f, hzd = 0.f;
            float hna = bhn, hnb = 0.f, hnc = 0.f, hnd = 0.f;
#pragma unroll
            for (int k = 0; k < 4; ++k) {
                hra = d2(wr2[k],      H0[k], hra);
                hrb = d2(wr2[k + 4],  H1[k], hrb);
                hrc = d2(wr2[k + 8],  H2[k], hrc);
                hrd = d2(wr2[k + 12], H3[k], hrd);
                hza = d2(wz2[k],      H0[k], hza);
                hzb = d2(wz2[k + 4],  H1[k], hzb);
                hzc = d2(wz2[k + 8],  H2[k], hzc);
                hzd = d2(wz2[k + 12], H3[k], hzd);
                hna = d2(wn2[k],      H0[k], hna);
                hnb = d2(wn2[k + 4],  H1[k], hnb);
                hnc = d2(wn2[k + 8],  H2[k], hnc);
                hnd = d2(wn2[k + 12], H3[k], hnd);
            }
            float hr = (hra + hrb) + (hrc + hrd);
            float hz = (hza + hzb) + (hzc + hzd);
            float hn = (hna + hnb) + (hnc + hnd);

            // ---- branch-free prefetch of next step's X ----
            int nt = (it + 1) & 15;
            float ner = xg[Tq][nt][mc];
            float nez = xg[2 + Tq][nt][mc];
            float nxn = xg[4 + Tq][nt][mc];

            // ---- gates + update, exp-factored sigmoids ----
            // sigma(x+h) = rcp(1 + exp(-x)*exp(-h)),  exp(-x) precomputed
            float r = frcp(fmaf(er, __expf(-hr), 1.f));
            float z = frcp(fmaf(ez, __expf(-hz), 1.f));
            float n = 1.f - 2.f * frcp(__expf(2.f * (xn + r * hn)) + 1.f);
            h_l = (1.f - z) * n + z * h_l;

            // ---- publish h as f16 (no DPP/pack on the path) ----
            if (l < 32) hlds16[l] = (_Float16)h_l;
            cfence();

            er = ner; ez = nez; xn = nxn;
        }
        __syncthreads();
    }

    if (l < 32) h_out[c * 32 + m] = h_l;
}

// ---------------------------------------------------------------------------
// K5: classifier. out[i,o] = sum_k clf_w[o,k]*h2[i,k] + clf_b[o]  (fp32 out)
// ---------------------------------------------------------------------------
__global__ void clf_kernel(const float* __restrict__ h2v, const float* __restrict__ w,
                           const float* __restrict__ bias, float* __restrict__ out) {
    int idx = blockIdx.x * 256 + threadIdx.x;      // 0..3071
    if (idx >= 3072) return;
    int i = idx / 3, o = idx - i * 3;
    float s = bias[o];
#pragma unroll
    for (int k = 0; k < 32; ++k) s += w[o * 32 + k] * h2v[i * 32 + k];
    out[idx] = s;
}

extern "C" void kernel_launch(void* const* d_in, const int* in_sizes, int n_in,
                              void* d_out, int out_size, void* d_ws, size_t ws_size,
                              hipStream_t stream) {
    const float* x       = (const float*)d_in[0];
    const float* p1w     = (const float*)d_in[1];
    const float* p1b     = (const float*)d_in[2];
    const float* g1_wih  = (const float*)d_in[3];
    const float* g1_whh  = (const float*)d_in[4];
    const float* g1_bih  = (const float*)d_in[5];
    const float* g1_bhh  = (const float*)d_in[6];
    const float* p2w     = (const float*)d_in[7];
    const float* p2b     = (const float*)d_in[8];
    const float* g2_wih  = (const float*)d_in[9];
    const float* g2_whh  = (const float*)d_in[10];
    const float* g2_bih  = (const float*)d_in[11];
    const float* g2_bhh  = (const float*)d_in[12];
    const float* clfw    = (const float*)d_in[13];
    const float* clfb    = (const float*)d_in[14];

    // Workspace layout (reused across stages; 3 x 32768 floats = 384 KB):
    float* ws = (float*)d_ws;
    float* A  = ws;              // A1 then A2
    float* Bt = ws + 32768;      // B1 then B2
    float* h  = ws + 65536;      // h1 then h2

    proj1_kernel<<<128, 256, 0, stream>>>(x, p1w, p1b, A, Bt);
    gru_kernel<<<1024, 64, 0, stream>>>(A, Bt, g1_wih, g1_whh, g1_bih, g1_bhh, h);
    proj2_kernel<<<128, 256, 0, stream>>>(h, p2w, p2b, A, Bt);
    gru_kernel<<<1024, 64, 0, stream>>>(A, Bt, g2_wih, g2_whh, g2_bih, g2_bhh, h);
    clf_kernel<<<12, 256, 0, stream>>>(h, clfw, clfb, (float*)d_out);
}